// Round 4
// baseline (174.274 us; speedup 1.0000x reference)
//
#include <hip/hip_runtime.h>

#define SQRT2f 1.41421356237309515f
#define SQRT3f 1.73205080756887729f

__device__ __forceinline__ float2 cmul(float2 a, float2 b) {
  return make_float2(a.x*b.x - a.y*b.y, a.x*b.y + a.y*b.x);
}
__device__ __forceinline__ float2 cadd(float2 a, float2 b) {
  return make_float2(a.x + b.x, a.y + b.y);
}

// ---- 9x9 beamsplitter expm(theta*BS_GEN), block-sparse closed form ----
// p = row-triple {0,1,2},{3,4,5},{6,7,8}; cs = (cos t, sin t); S = pair stride
template<int S>
__device__ __forceinline__ void bs_apply(const float2* __restrict__ cur,
                                         float2* __restrict__ nxt,
                                         int base, int p, float2 cs) {
  const float c = cs.x, s = cs.y;
  const float c2 = c*c - s*s, s2 = 2.f*c*s;
  const float cc = c*c, ss = s*s, rcs = SQRT2f*c*s;
  if (p == 0) {
    float2 a0 = cur[base];
    float2 a1 = cur[base+S],   a3 = cur[base+3*S];
    float2 a2 = cur[base+2*S], a4 = cur[base+4*S], a6 = cur[base+6*S];
    nxt[base]     = a0;
    nxt[base+S]   = make_float2(c*a1.x - s*a3.x, c*a1.y - s*a3.y);
    nxt[base+2*S] = make_float2(cc*a2.x - rcs*a4.x + ss*a6.x,
                                cc*a2.y - rcs*a4.y + ss*a6.y);
  } else if (p == 1) {
    float2 a1 = cur[base+S],   a3 = cur[base+3*S];
    float2 a2 = cur[base+2*S], a4 = cur[base+4*S], a6 = cur[base+6*S];
    float2 a5 = cur[base+5*S], a7 = cur[base+7*S];
    nxt[base+3*S] = make_float2(s*a1.x + c*a3.x, s*a1.y + c*a3.y);
    nxt[base+4*S] = make_float2(rcs*a2.x + c2*a4.x - rcs*a6.x,
                                rcs*a2.y + c2*a4.y - rcs*a6.y);
    nxt[base+5*S] = make_float2(c2*a5.x - s2*a7.x, c2*a5.y - s2*a7.y);
  } else {
    float2 a2 = cur[base+2*S], a4 = cur[base+4*S], a6 = cur[base+6*S];
    float2 a5 = cur[base+5*S], a7 = cur[base+7*S];
    float2 a8 = cur[base+8*S];
    nxt[base+6*S] = make_float2(ss*a2.x + rcs*a4.x + cc*a6.x,
                                ss*a2.y + rcs*a4.y + cc*a6.y);
    nxt[base+7*S] = make_float2(s2*a5.x + c2*a7.x, s2*a5.y + c2*a7.y);
    nxt[base+8*S] = a8;
  }
}

// ---- fused 2-mode squeeze+phase: out[i,i'] = sum A[p][j] B[i'][j'] in[j,j'] ----
// A,B = 5-nonzero column-scaled SQ matrices: (m00, m02, m11, m20, m22).
// Pair of modes (m, m+1): mode-m stride = 3*SP, mode-(m+1) stride = SP.
template<int SP>
__device__ __forceinline__ void sqf_apply(const float2* __restrict__ cur,
                                          float2* __restrict__ nxt,
                                          int rbase, int p,
                                          const float2* __restrict__ A,
                                          float2 b00, float2 b02, float2 b11,
                                          float2 b20, float2 b22) {
  const int S1 = SP, S3 = 3*SP;
  if (p != 1) {
    float2 u0 = cur[rbase],      u1 = cur[rbase+S1],      u2 = cur[rbase+2*S1];
    float2 w0 = cur[rbase+2*S3], w1 = cur[rbase+2*S3+S1], w2 = cur[rbase+2*S3+2*S1];
    float2 tu0 = cadd(cmul(b00,u0), cmul(b02,u2));
    float2 tu1 = cmul(b11,u1);
    float2 tu2 = cadd(cmul(b20,u0), cmul(b22,u2));
    float2 tw0 = cadd(cmul(b00,w0), cmul(b02,w2));
    float2 tw1 = cmul(b11,w1);
    float2 tw2 = cadd(cmul(b20,w0), cmul(b22,w2));
    float2 aj0 = (p==0) ? A[0] : A[3];
    float2 aj2 = (p==0) ? A[1] : A[4];
    const int wb = rbase + p*S3;
    nxt[wb]      = cadd(cmul(aj0,tu0), cmul(aj2,tw0));
    nxt[wb+S1]   = cadd(cmul(aj0,tu1), cmul(aj2,tw1));
    nxt[wb+2*S1] = cadd(cmul(aj0,tu2), cmul(aj2,tw2));
  } else {
    float2 v0 = cur[rbase+S3], v1 = cur[rbase+S3+S1], v2 = cur[rbase+S3+2*S1];
    float2 a = A[2];
    const int wb = rbase + S3;
    nxt[wb]      = cmul(a, cadd(cmul(b00,v0), cmul(b02,v2)));
    nxt[wb+S1]   = cmul(a, cmul(b11,v1));
    nxt[wb+2*S1] = cmul(a, cadd(cmul(b20,v0), cmul(b22,v2)));
  }
}

// ---- fused 2-mode disp+phase+kerr (dense complex 3x3 x 3x3) ----
template<int SP>
__device__ __forceinline__ void dpf_apply(const float2* __restrict__ cur,
                                          float2* __restrict__ nxt,
                                          int rbase, int p,
                                          float2 a0, float2 a1, float2 a2,
                                          const float2* __restrict__ B) {
  const int S1 = SP, S3 = 3*SP;
  float2 B0=B[0],B1=B[1],B2=B[2],B3=B[3],B4=B[4],B5=B[5],B6=B[6],B7=B[7],B8=B[8];
  float2 o0 = make_float2(0.f,0.f), o1 = o0, o2 = o0;
#pragma unroll
  for (int j = 0; j < 3; ++j) {
    float2 a = (j==0) ? a0 : (j==1) ? a1 : a2;
    const int rb = rbase + j*S3;
    float2 v0 = cur[rb], v1 = cur[rb+S1], v2 = cur[rb+2*S1];
    float2 t0 = cadd(cadd(cmul(B0,v0), cmul(B1,v1)), cmul(B2,v2));
    float2 t1 = cadd(cadd(cmul(B3,v0), cmul(B4,v1)), cmul(B5,v2));
    float2 t2 = cadd(cadd(cmul(B6,v0), cmul(B7,v1)), cmul(B8,v2));
    o0 = cadd(o0, cmul(a,t0));
    o1 = cadd(o1, cmul(a,t1));
    o2 = cadd(o2, cmul(a,t2));
  }
  const int wb = rbase + p*S3;
  nxt[wb] = o0; nxt[wb+S1] = o1; nxt[wb+2*S1] = o2;
}

#define BASE4(g, s0,s1,s2,s3) ({ int _d=(g); int _b=(_d%3)*(s0); _d/=3; \
  _b += (_d%3)*(s1); _d/=3; _b += (_d%3)*(s2); _d/=3; _b += (_d%3)*(s3); _b; })
#define BASE5(g, s0,s1,s2,s3,s4) ({ int _d=(g); int _b=(_d%3)*(s0); _d/=3; \
  _b += (_d%3)*(s1); _d/=3; _b += (_d%3)*(s2); _d/=3; _b += (_d%3)*(s3); _d/=3; \
  _b += (_d%3)*(s4); _b; })

// gtab layout (float2):
// [0,180)    BS (c,s):      idx = L*30 + pass*15 + n
// [180,360)  SQM (5/mode):  180 + (L*6+mode)*5 + e   e: m00,m02,m11,m20,m22
// [360,684)  DPM (9/mode):  360 + (L*6+mode)*9 + i*3+j
// [684,696)  init disp (sw,cw) per state,mode: 684 + st*6 + mode
__global__ __launch_bounds__(256, 2)
void cvnn_kernel(const float* __restrict__ x,
                 const float* __restrict__ th1,
                 const float* __restrict__ th2,
                 const float* __restrict__ sr,
                 const float* __restrict__ dr,
                 const float* __restrict__ kp,
                 float* __restrict__ out, int Btot) {
  __shared__ float2 psiBuf[2][2][729];   // [buffer][state][amp]
  __shared__ float2 gtab[696];
  __shared__ float red[2][24];

  const int tid = threadIdx.x;
  const int bidx = blockIdx.x;

  // ---- build gate table ----
  for (int f = tid; f < 696; f += 256) {
    float sn, cn; float2 v;
    if (f < 180) {
      int L = f/30, r2 = f%30, pass = r2/15, n = r2%15;
      float th = (pass ? th2 : th1)[L*35 + n];
      sincosf(th, &sn, &cn); v = make_float2(cn, sn);
    } else if (f < 360) {
      int idx = f - 180; int Lm = idx/5, e = idx%5;
      int L = Lm/6, mode = Lm%6;
      float Sq, Cq; sincosf(0.25f*SQRT2f*sr[L*6+mode], &Sq, &Cq);
      float2 ph = make_float2(1.f, 0.f);
      if (mode < 5) { float ps, pc; sincosf(th1[L*35+29+mode], &ps, &pc);
                      ph = make_float2(pc, ps); }
      float2 ph2 = cmul(ph, ph);
      if      (e == 0) v = make_float2(Cq, 0.f);
      else if (e == 1) v = make_float2(Sq*ph2.x, Sq*ph2.y);
      else if (e == 2) v = ph;
      else if (e == 3) v = make_float2(-Sq, 0.f);
      else             v = make_float2(Cq*ph2.x, Cq*ph2.y);
    } else if (f < 684) {
      int idx = f - 360; int Lm = idx/9, e = idx%9;
      int L = Lm/6, mode = Lm%6; int i = e/3, j = e%3;
      sincosf(SQRT3f*dr[L*6+mode], &sn, &cn);
      float sw = sn*(1.f/SQRT3f), cw = (1.f-cn)*(1.f/3.f);
      float U;
      if      (i==0) U = (j==0) ? (1.f-cw)     : (j==1) ? (-sw)         : (SQRT2f*cw);
      else if (i==1) U = (j==0) ? (sw)         : (j==1) ? (1.f-3.f*cw)  : (-SQRT2f*sw);
      else           U = (j==0) ? (SQRT2f*cw)  : (j==1) ? (SQRT2f*sw)   : (1.f-2.f*cw);
      float2 ph = make_float2(1.f, 0.f);
      if (mode < 5) { float ps, pc; sincosf(th2[L*35+29+mode], &ps, &pc);
                      ph = make_float2(pc, ps); }
      float2 phj = (j==0) ? make_float2(1.f,0.f) : (j==1) ? ph : cmul(ph, ph);
      float ks, kc; sincosf(0.001f*kp[L*6+mode], &ks, &kc);
      float2 k1 = make_float2(kc, ks);
      float2 ki = (i==0) ? make_float2(1.f,0.f)
                : (i==1) ? k1 : cmul(cmul(k1,k1), cmul(k1,k1));
      float2 t = cmul(phj, ki);
      v = make_float2(U*t.x, U*t.y);
    } else {
      int idx = f - 684; int st = idx/6, mode = idx%6;
      int b = bidx*2 + st; if (b >= Btot) b = Btot - 1;
      sincosf(SQRT3f*x[b*6 + mode], &sn, &cn);
      v = make_float2(sn*(1.f/SQRT3f), (1.f-cn)*(1.f/3.f));
    }
    gtab[f] = v;
  }
  __syncthreads();

  // ---- init: product state of displaced |0> ----
  for (int idx = tid; idx < 729; idx += 256) {
    float pr0 = 1.f, pr1 = 1.f; int d = idx;
#pragma unroll
    for (int mm = 5; mm >= 0; --mm) {
      int n = d % 3; d /= 3;
      float2 d0 = gtab[684 + mm];
      float2 d1 = gtab[690 + mm];
      pr0 *= (n==0) ? (1.f-d0.y) : (n==1) ? d0.x : SQRT2f*d0.y;
      pr1 *= (n==0) ? (1.f-d1.y) : (n==1) ? d1.x : SQRT2f*d1.y;
    }
    psiBuf[0][0][idx] = make_float2(pr0, 0.f);
    psiBuf[0][1][idx] = make_float2(pr1, 0.f);
  }

  // ---- per-thread bases ----
  const bool act = (tid < 243);
  const int p  = tid / 81;
  const int g2 = tid % 81;
  const int b20 = BASE4(g2, 1, 3, 9, 27);    // pair(0,1) SP=81 / BS k=0
  const int b21 = BASE4(g2, 1, 3, 9, 243);   // BS k=1 SP=27
  const int b22 = BASE4(g2, 1, 3, 81, 243);  // pair(2,3) SP=9 / BS k=2
  const int b23 = BASE4(g2, 1, 27, 81, 243); // BS k=3 SP=3
  const int b24 = BASE4(g2, 9, 27, 81, 243); // pair(4,5) SP=1 / BS k=4
  const int b50 = BASE5(tid, 1, 3, 9, 27, 81);   // mode0 S=243 (XEXP)
  const int b51 = BASE5(tid, 1, 3, 9, 27, 243);
  const int b52 = BASE5(tid, 1, 3, 9, 81, 243);
  const int b53 = BASE5(tid, 1, 3, 27, 81, 243);
  const int b54 = BASE5(tid, 1, 9, 27, 81, 243);
  const int b55 = BASE5(tid, 3, 9, 27, 81, 243);

  int cb = 0;
  __syncthreads();

#define BSG2(SS, BASE, IDX) { if (act) { float2 cs_ = gtab[IDX]; \
    bs_apply<SS>(&psiBuf[cb][0][0], &psiBuf[cb^1][0][0], BASE, p, cs_); \
    bs_apply<SS>(&psiBuf[cb][1][0], &psiBuf[cb^1][1][0], BASE, p, cs_); } \
  __syncthreads(); cb ^= 1; }

#define SQF2(SS, BASE, LL, m) { if (act) { \
    const float2* A_ = &gtab[180 + ((LL)*6+(m))*5]; \
    float2 q00=A_[5], q02=A_[6], q11=A_[7], q20=A_[8], q22=A_[9]; \
    sqf_apply<SS>(&psiBuf[cb][0][0], &psiBuf[cb^1][0][0], BASE, p, A_, q00,q02,q11,q20,q22); \
    sqf_apply<SS>(&psiBuf[cb][1][0], &psiBuf[cb^1][1][0], BASE, p, A_, q00,q02,q11,q20,q22); } \
  __syncthreads(); cb ^= 1; }

#define DPF2(SS, BASE, LL, m) { if (act) { \
    const float2* R_ = &gtab[360 + ((LL)*6+(m))*9]; \
    float2 a0_ = R_[p*3+0], a1_ = R_[p*3+1], a2_ = R_[p*3+2]; \
    const float2* B_ = R_ + 9; \
    dpf_apply<SS>(&psiBuf[cb][0][0], &psiBuf[cb^1][0][0], BASE, p, a0_,a1_,a2_, B_); \
    dpf_apply<SS>(&psiBuf[cb][1][0], &psiBuf[cb^1][1][0], BASE, p, a0_,a1_,a2_, B_); } \
  __syncthreads(); cb ^= 1; }

  for (int L = 0; L < 6; ++L) {
    {  // pass 1: interferometer(theta_1) then squeeze (phases folded into SQ)
      const int o = L*30;
      BSG2(81, b20, o+0);  BSG2(9, b22, o+1);  BSG2(1, b24, o+2);
      BSG2(27, b21, o+3);  BSG2(3, b23, o+4);
      BSG2(81, b20, o+5);  BSG2(9, b22, o+6);  BSG2(1, b24, o+7);
      BSG2(27, b21, o+8);  BSG2(3, b23, o+9);
      BSG2(81, b20, o+10); BSG2(9, b22, o+11); BSG2(1, b24, o+12);
      BSG2(27, b21, o+13); BSG2(3, b23, o+14);
      SQF2(81, b20, L, 0); SQF2(9, b22, L, 2); SQF2(1, b24, L, 4);
    }
    {  // pass 2: interferometer(theta_2) then disp+kerr (phases+kerr folded)
      const int o = L*30 + 15;
      BSG2(81, b20, o+0);  BSG2(9, b22, o+1);  BSG2(1, b24, o+2);
      BSG2(27, b21, o+3);  BSG2(3, b23, o+4);
      BSG2(81, b20, o+5);  BSG2(9, b22, o+6);  BSG2(1, b24, o+7);
      BSG2(27, b21, o+8);  BSG2(3, b23, o+9);
      BSG2(81, b20, o+10); BSG2(9, b22, o+11); BSG2(1, b24, o+12);
      BSG2(27, b21, o+13); BSG2(3, b23, o+14);
      DPF2(81, b20, L, 0); DPF2(9, b22, L, 2); DPF2(1, b24, L, 4);
    }
  }

  // ---- <X_m> for both states ----
  const int lane = tid & 63, wid = tid >> 6;
  const float2* fin0 = &psiBuf[cb][0][0];
  const float2* fin1 = &psiBuf[cb][1][0];
#define XEXP2(m, SS, BASE) { \
    float p0 = 0.f, p1 = 0.f; \
    if (act) { \
      float2 a_ = fin0[BASE]; float2 b_ = fin0[(BASE)+(SS)]; float2 c_ = fin0[(BASE)+2*(SS)]; \
      p0 = 2.f*(a_.x*b_.x + a_.y*b_.y) + 2.f*SQRT2f*(b_.x*c_.x + b_.y*c_.y); \
      a_ = fin1[BASE]; b_ = fin1[(BASE)+(SS)]; c_ = fin1[(BASE)+2*(SS)]; \
      p1 = 2.f*(a_.x*b_.x + a_.y*b_.y) + 2.f*SQRT2f*(b_.x*c_.x + b_.y*c_.y); \
    } \
    for (int off = 32; off > 0; off >>= 1) { \
      p0 += __shfl_down(p0, off); p1 += __shfl_down(p1, off); } \
    if (lane == 0) { red[0][(m)*4 + wid] = p0; red[1][(m)*4 + wid] = p1; } \
  }
  XEXP2(0, 243, b50); XEXP2(1, 81, b51); XEXP2(2, 27, b52);
  XEXP2(3, 9,  b53); XEXP2(4, 3,  b54); XEXP2(5, 1,  b55);
  __syncthreads();
  if (tid < 12) {
    int st = tid/6, m = tid%6;
    float vsum = red[st][m*4+0] + red[st][m*4+1] + red[st][m*4+2] + red[st][m*4+3];
    int b = bidx*2 + st;
    if (b < Btot) out[b*6 + m] = vsum;
  }
}

extern "C" void kernel_launch(void* const* d_in, const int* in_sizes, int n_in,
                              void* d_out, int out_size, void* d_ws, size_t ws_size,
                              hipStream_t stream) {
  const float* x  = (const float*)d_in[0];
  const float* t1 = (const float*)d_in[1];
  const float* t2 = (const float*)d_in[2];
  const float* sr = (const float*)d_in[3];
  const float* dr = (const float*)d_in[4];
  const float* kp = (const float*)d_in[5];
  const int B = in_sizes[0] / 6;
  const int nb = (B + 1) / 2;
  cvnn_kernel<<<nb, 256, 0, stream>>>(x, t1, t2, sr, dr, kp, (float*)d_out, B);
}

// Round 5
// 155.758 us; speedup vs baseline: 1.1189x; 1.1189x over previous
//
#include <hip/hip_runtime.h>

#define SQRT2f 1.41421356237309515f
#define SQRT3f 1.73205080756887729f

__device__ __forceinline__ float2 cmul(float2 a, float2 b) {
  return make_float2(a.x*b.x - a.y*b.y, a.x*b.y + a.y*b.x);
}
__device__ __forceinline__ float2 cadd(float2 a, float2 b) {
  return make_float2(a.x + b.x, a.y + b.y);
}

// ---- 9x9 beamsplitter expm(theta*BS_GEN), block-sparse closed form ----
template<int S>
__device__ __forceinline__ void bs_apply(const float2* __restrict__ cur,
                                         float2* __restrict__ nxt,
                                         int base, int p, float2 cs) {
  const float c = cs.x, s = cs.y;
  const float c2 = c*c - s*s, s2 = 2.f*c*s;
  const float cc = c*c, ss = s*s, rcs = SQRT2f*c*s;
  if (p == 0) {
    float2 a0 = cur[base];
    float2 a1 = cur[base+S],   a3 = cur[base+3*S];
    float2 a2 = cur[base+2*S], a4 = cur[base+4*S], a6 = cur[base+6*S];
    nxt[base]     = a0;
    nxt[base+S]   = make_float2(c*a1.x - s*a3.x, c*a1.y - s*a3.y);
    nxt[base+2*S] = make_float2(cc*a2.x - rcs*a4.x + ss*a6.x,
                                cc*a2.y - rcs*a4.y + ss*a6.y);
  } else if (p == 1) {
    float2 a1 = cur[base+S],   a3 = cur[base+3*S];
    float2 a2 = cur[base+2*S], a4 = cur[base+4*S], a6 = cur[base+6*S];
    float2 a5 = cur[base+5*S], a7 = cur[base+7*S];
    nxt[base+3*S] = make_float2(s*a1.x + c*a3.x, s*a1.y + c*a3.y);
    nxt[base+4*S] = make_float2(rcs*a2.x + c2*a4.x - rcs*a6.x,
                                rcs*a2.y + c2*a4.y - rcs*a6.y);
    nxt[base+5*S] = make_float2(c2*a5.x - s2*a7.x, c2*a5.y - s2*a7.y);
  } else {
    float2 a2 = cur[base+2*S], a4 = cur[base+4*S], a6 = cur[base+6*S];
    float2 a5 = cur[base+5*S], a7 = cur[base+7*S];
    float2 a8 = cur[base+8*S];
    nxt[base+6*S] = make_float2(ss*a2.x + rcs*a4.x + cc*a6.x,
                                ss*a2.y + rcs*a4.y + cc*a6.y);
    nxt[base+7*S] = make_float2(s2*a5.x + c2*a7.x, s2*a5.y + c2*a7.y);
    nxt[base+8*S] = a8;
  }
}

// ---- fused 2-mode squeeze(+phase): A on mode m (rows p), B on mode m+1 ----
template<int SP>
__device__ __forceinline__ void sqf_apply(const float2* __restrict__ cur,
                                          float2* __restrict__ nxt,
                                          int rbase, int p,
                                          const float2* __restrict__ A,
                                          float2 b00, float2 b02, float2 b11,
                                          float2 b20, float2 b22) {
  const int S1 = SP, S3 = 3*SP;
  if (p != 1) {
    float2 u0 = cur[rbase],      u1 = cur[rbase+S1],      u2 = cur[rbase+2*S1];
    float2 w0 = cur[rbase+2*S3], w1 = cur[rbase+2*S3+S1], w2 = cur[rbase+2*S3+2*S1];
    float2 tu0 = cadd(cmul(b00,u0), cmul(b02,u2));
    float2 tu1 = cmul(b11,u1);
    float2 tu2 = cadd(cmul(b20,u0), cmul(b22,u2));
    float2 tw0 = cadd(cmul(b00,w0), cmul(b02,w2));
    float2 tw1 = cmul(b11,w1);
    float2 tw2 = cadd(cmul(b20,w0), cmul(b22,w2));
    float2 aj0 = (p==0) ? A[0] : A[3];
    float2 aj2 = (p==0) ? A[1] : A[4];
    const int wb = rbase + p*S3;
    nxt[wb]      = cadd(cmul(aj0,tu0), cmul(aj2,tw0));
    nxt[wb+S1]   = cadd(cmul(aj0,tu1), cmul(aj2,tw1));
    nxt[wb+2*S1] = cadd(cmul(aj0,tu2), cmul(aj2,tw2));
  } else {
    float2 v0 = cur[rbase+S3], v1 = cur[rbase+S3+S1], v2 = cur[rbase+S3+2*S1];
    float2 a = A[2];
    const int wb = rbase + S3;
    nxt[wb]      = cmul(a, cadd(cmul(b00,v0), cmul(b02,v2)));
    nxt[wb+S1]   = cmul(a, cmul(b11,v1));
    nxt[wb+2*S1] = cmul(a, cadd(cmul(b20,v0), cmul(b22,v2)));
  }
}

// ---- fused 2-mode disp(+phase+kerr): dense complex 3x3 (A rows) x 3x3 (B) ----
template<int SP>
__device__ __forceinline__ void dpf_apply(const float2* __restrict__ cur,
                                          float2* __restrict__ nxt,
                                          int rbase, int p,
                                          float2 a0, float2 a1, float2 a2,
                                          const float2* __restrict__ B) {
  const int S1 = SP, S3 = 3*SP;
  float2 B0=B[0],B1=B[1],B2=B[2],B3=B[3],B4=B[4],B5=B[5],B6=B[6],B7=B[7],B8=B[8];
  float2 o0 = make_float2(0.f,0.f), o1 = o0, o2 = o0;
#pragma unroll
  for (int j = 0; j < 3; ++j) {
    float2 a = (j==0) ? a0 : (j==1) ? a1 : a2;
    const int rb = rbase + j*S3;
    float2 v0 = cur[rb], v1 = cur[rb+S1], v2 = cur[rb+2*S1];
    float2 t0 = cadd(cadd(cmul(B0,v0), cmul(B1,v1)), cmul(B2,v2));
    float2 t1 = cadd(cadd(cmul(B3,v0), cmul(B4,v1)), cmul(B5,v2));
    float2 t2 = cadd(cadd(cmul(B6,v0), cmul(B7,v1)), cmul(B8,v2));
    o0 = cadd(o0, cmul(a,t0));
    o1 = cadd(o1, cmul(a,t1));
    o2 = cadd(o2, cmul(a,t2));
  }
  const int wb = rbase + p*S3;
  nxt[wb] = o0; nxt[wb+S1] = o1; nxt[wb+2*S1] = o2;
}

#define BASE4(g, s0,s1,s2,s3) ({ int _d=(g); int _b=(_d%3)*(s0); _d/=3; \
  _b += (_d%3)*(s1); _d/=3; _b += (_d%3)*(s2); _d/=3; _b += (_d%3)*(s3); _b; })
#define BASE5(g, s0,s1,s2,s3,s4) ({ int _d=(g); int _b=(_d%3)*(s0); _d/=3; \
  _b += (_d%3)*(s1); _d/=3; _b += (_d%3)*(s2); _d/=3; _b += (_d%3)*(s3); _d/=3; \
  _b += (_d%3)*(s4); _b; })

// gtab layout (float2):
// [0,180)    BS (c,s):      idx = L*30 + pass*15 + n
// [180,360)  SQM (5/mode):  180 + (L*6+mode)*5 + e   e: m00,m02,m11,m20,m22
// [360,684)  DPM (9/mode):  360 + (L*6+mode)*9 + i*3+j
// [684,690)  init disp (sw,cw) per mode
__global__ __launch_bounds__(256, 4)
void cvnn_kernel(const float* __restrict__ x,
                 const float* __restrict__ th1,
                 const float* __restrict__ th2,
                 const float* __restrict__ sr,
                 const float* __restrict__ dr,
                 const float* __restrict__ kp,
                 float* __restrict__ out) {
  __shared__ float2 psiBuf[2][729];
  __shared__ float2 gtab[690];
  __shared__ float red[24];

  const int tid = threadIdx.x;
  const int bidx = blockIdx.x;

  // ---- build gate table ----
  for (int f = tid; f < 690; f += 256) {
    float sn, cn; float2 v;
    if (f < 180) {
      int L = f/30, r2 = f%30, pass = r2/15, n = r2%15;
      float th = (pass ? th2 : th1)[L*35 + n];
      sincosf(th, &sn, &cn); v = make_float2(cn, sn);
    } else if (f < 360) {
      int idx = f - 180; int Lm = idx/5, e = idx%5;
      int L = Lm/6, mode = Lm%6;
      float Sq, Cq; sincosf(0.25f*SQRT2f*sr[L*6+mode], &Sq, &Cq);
      float2 ph = make_float2(1.f, 0.f);
      if (mode < 5) { float ps, pc; sincosf(th1[L*35+29+mode], &ps, &pc);
                      ph = make_float2(pc, ps); }
      float2 ph2 = cmul(ph, ph);
      if      (e == 0) v = make_float2(Cq, 0.f);
      else if (e == 1) v = make_float2(Sq*ph2.x, Sq*ph2.y);
      else if (e == 2) v = ph;
      else if (e == 3) v = make_float2(-Sq, 0.f);
      else             v = make_float2(Cq*ph2.x, Cq*ph2.y);
    } else if (f < 684) {
      int idx = f - 360; int Lm = idx/9, e = idx%9;
      int L = Lm/6, mode = Lm%6; int i = e/3, j = e%3;
      sincosf(SQRT3f*dr[L*6+mode], &sn, &cn);
      float sw = sn*(1.f/SQRT3f), cw = (1.f-cn)*(1.f/3.f);
      float U;
      if      (i==0) U = (j==0) ? (1.f-cw)     : (j==1) ? (-sw)         : (SQRT2f*cw);
      else if (i==1) U = (j==0) ? (sw)         : (j==1) ? (1.f-3.f*cw)  : (-SQRT2f*sw);
      else           U = (j==0) ? (SQRT2f*cw)  : (j==1) ? (SQRT2f*sw)   : (1.f-2.f*cw);
      float2 ph = make_float2(1.f, 0.f);
      if (mode < 5) { float ps, pc; sincosf(th2[L*35+29+mode], &ps, &pc);
                      ph = make_float2(pc, ps); }
      float2 phj = (j==0) ? make_float2(1.f,0.f) : (j==1) ? ph : cmul(ph, ph);
      float ks, kc; sincosf(0.001f*kp[L*6+mode], &ks, &kc);
      float2 k1 = make_float2(kc, ks);
      float2 ki = (i==0) ? make_float2(1.f,0.f)
                : (i==1) ? k1 : cmul(cmul(k1,k1), cmul(k1,k1));
      float2 t = cmul(phj, ki);
      v = make_float2(U*t.x, U*t.y);
    } else {
      int mode = f - 684;
      sincosf(SQRT3f*x[bidx*6 + mode], &sn, &cn);
      v = make_float2(sn*(1.f/SQRT3f), (1.f-cn)*(1.f/3.f));
    }
    gtab[f] = v;
  }
  __syncthreads();

  // ---- init: product state of displaced |0> ----
  for (int idx = tid; idx < 729; idx += 256) {
    float pr = 1.f; int d = idx;
#pragma unroll
    for (int mm = 5; mm >= 0; --mm) {
      int n = d % 3; d /= 3;
      float2 dc = gtab[684 + mm];
      pr *= (n==0) ? (1.f-dc.y) : (n==1) ? dc.x : SQRT2f*dc.y;
    }
    psiBuf[0][idx] = make_float2(pr, 0.f);
  }

  // ---- per-thread bases ----
  const bool act = (tid < 243);
  const int p  = tid / 81;
  const int g2 = tid % 81;
  const int b20 = BASE4(g2, 1, 3, 9, 27);    // pair(0,1) SP=81 / BS k=0
  const int b21 = BASE4(g2, 1, 3, 9, 243);   // BS k=1 SP=27
  const int b22 = BASE4(g2, 1, 3, 81, 243);  // pair(2,3) SP=9 / BS k=2
  const int b23 = BASE4(g2, 1, 27, 81, 243); // BS k=3 SP=3
  const int b24 = BASE4(g2, 9, 27, 81, 243); // pair(4,5) SP=1 / BS k=4
  const int b50 = BASE5(tid, 1, 3, 9, 27, 81);   // mode m XEXP strides
  const int b51 = BASE5(tid, 1, 3, 9, 27, 243);
  const int b52 = BASE5(tid, 1, 3, 9, 81, 243);
  const int b53 = BASE5(tid, 1, 3, 27, 81, 243);
  const int b54 = BASE5(tid, 1, 9, 27, 81, 243);
  const int b55 = BASE5(tid, 3, 9, 27, 81, 243);

  int cb = 0;
  __syncthreads();

#define BSG(SS, BASE, IDX) { if (act) { float2 cs_ = gtab[IDX]; \
    bs_apply<SS>(&psiBuf[cb][0], &psiBuf[cb^1][0], BASE, p, cs_); } \
  __syncthreads(); cb ^= 1; }

#define SQF(SS, BASE, LL, m) { if (act) { \
    const float2* A_ = &gtab[180 + ((LL)*6+(m))*5]; \
    float2 q00=A_[5], q02=A_[6], q11=A_[7], q20=A_[8], q22=A_[9]; \
    sqf_apply<SS>(&psiBuf[cb][0], &psiBuf[cb^1][0], BASE, p, A_, q00,q02,q11,q20,q22); } \
  __syncthreads(); cb ^= 1; }

#define DPF(SS, BASE, LL, m) { if (act) { \
    const float2* R_ = &gtab[360 + ((LL)*6+(m))*9]; \
    float2 a0_ = R_[p*3+0], a1_ = R_[p*3+1], a2_ = R_[p*3+2]; \
    const float2* B_ = R_ + 9; \
    dpf_apply<SS>(&psiBuf[cb][0], &psiBuf[cb^1][0], BASE, p, a0_,a1_,a2_, B_); } \
  __syncthreads(); cb ^= 1; }

  for (int L = 0; L < 6; ++L) {
    {  // pass 1: interferometer(theta_1) then squeeze (phases folded into SQ)
      const int o = L*30;
      BSG(81, b20, o+0);  BSG(9, b22, o+1);  BSG(1, b24, o+2);
      BSG(27, b21, o+3);  BSG(3, b23, o+4);
      BSG(81, b20, o+5);  BSG(9, b22, o+6);  BSG(1, b24, o+7);
      BSG(27, b21, o+8);  BSG(3, b23, o+9);
      BSG(81, b20, o+10); BSG(9, b22, o+11); BSG(1, b24, o+12);
      BSG(27, b21, o+13); BSG(3, b23, o+14);
      SQF(81, b20, L, 0); SQF(9, b22, L, 2); SQF(1, b24, L, 4);
    }
    {  // pass 2: interferometer(theta_2) then disp+kerr (phases+kerr folded)
      const int o = L*30 + 15;
      BSG(81, b20, o+0);  BSG(9, b22, o+1);  BSG(1, b24, o+2);
      BSG(27, b21, o+3);  BSG(3, b23, o+4);
      BSG(81, b20, o+5);  BSG(9, b22, o+6);  BSG(1, b24, o+7);
      BSG(27, b21, o+8);  BSG(3, b23, o+9);
      BSG(81, b20, o+10); BSG(9, b22, o+11); BSG(1, b24, o+12);
      BSG(27, b21, o+13); BSG(3, b23, o+14);
      DPF(81, b20, L, 0); DPF(9, b22, L, 2); DPF(1, b24, L, 4);
    }
  }

  // ---- <X_m> ----
  const int lane = tid & 63, wid = tid >> 6;
  const float2* fin = &psiBuf[cb][0];
#define XEXP(m, SS, BASE) { \
    float part = 0.f; \
    if (act) { \
      float2 a_ = fin[BASE]; float2 b_ = fin[(BASE)+(SS)]; float2 c_ = fin[(BASE)+2*(SS)]; \
      part = 2.f*(a_.x*b_.x + a_.y*b_.y) + 2.f*SQRT2f*(b_.x*c_.x + b_.y*c_.y); \
    } \
    for (int off = 32; off > 0; off >>= 1) part += __shfl_down(part, off); \
    if (lane == 0) red[(m)*4 + wid] = part; \
  }
  XEXP(0, 243, b50); XEXP(1, 81, b51); XEXP(2, 27, b52);
  XEXP(3, 9,  b53); XEXP(4, 3,  b54); XEXP(5, 1,  b55);
  __syncthreads();
  if (tid < 6) {
    float v = red[tid*4+0] + red[tid*4+1] + red[tid*4+2] + red[tid*4+3];
    out[bidx*6 + tid] = v;
  }
}

extern "C" void kernel_launch(void* const* d_in, const int* in_sizes, int n_in,
                              void* d_out, int out_size, void* d_ws, size_t ws_size,
                              hipStream_t stream) {
  const float* x  = (const float*)d_in[0];
  const float* t1 = (const float*)d_in[1];
  const float* t2 = (const float*)d_in[2];
  const float* sr = (const float*)d_in[3];
  const float* dr = (const float*)d_in[4];
  const float* kp = (const float*)d_in[5];
  const int B = in_sizes[0] / 6;
  cvnn_kernel<<<B, 256, 0, stream>>>(x, t1, t2, sr, dr, kp, (float*)d_out);
}

// Round 6
// 124.255 us; speedup vs baseline: 1.4026x; 1.2535x over previous
//
#include <hip/hip_runtime.h>

#define SQRT2f 1.41421356237309515f
#define SQRT3f 1.73205080756887729f

__device__ __forceinline__ float2 cmul(float2 a, float2 b) {
  return make_float2(a.x*b.x - a.y*b.y, a.x*b.y + a.y*b.x);
}
__device__ __forceinline__ float2 cadd(float2 a, float2 b) {
  return make_float2(a.x + b.x, a.y + b.y);
}

// ---- full 9x9 beamsplitter on one nonet, in place (rows 0,8 identity) ----
// amp[q] at psi[base + q*SP], q = 3*n_k + n_{k+1}; SP = stride of mode k+1
template<int SP>
__device__ __forceinline__ void bs_nonet(float2* __restrict__ psi, int base,
                                         float2 cs) {
  const float c = cs.x, s = cs.y;
  const float c2 = c*c - s*s, s2 = 2.f*c*s;
  const float cc = c*c, ss = s*s, rcs = SQRT2f*c*s;
  float2 a1 = psi[base+SP],   a3 = psi[base+3*SP];
  float2 a2 = psi[base+2*SP], a4 = psi[base+4*SP], a6 = psi[base+6*SP];
  float2 a5 = psi[base+5*SP], a7 = psi[base+7*SP];
  psi[base+SP]   = make_float2(c*a1.x - s*a3.x, c*a1.y - s*a3.y);
  psi[base+3*SP] = make_float2(s*a1.x + c*a3.x, s*a1.y + c*a3.y);
  psi[base+2*SP] = make_float2(cc*a2.x - rcs*a4.x + ss*a6.x,
                               cc*a2.y - rcs*a4.y + ss*a6.y);
  psi[base+4*SP] = make_float2(rcs*a2.x + c2*a4.x - rcs*a6.x,
                               rcs*a2.y + c2*a4.y - rcs*a6.y);
  psi[base+6*SP] = make_float2(ss*a2.x + rcs*a4.x + cc*a6.x,
                               ss*a2.y + rcs*a4.y + cc*a6.y);
  psi[base+5*SP] = make_float2(c2*a5.x - s2*a7.x, c2*a5.y - s2*a7.y);
  psi[base+7*SP] = make_float2(s2*a5.x + c2*a7.x, s2*a5.y + c2*a7.y);
}

// ---- fused squeeze(+phase) on one nonet: sparse A (mode a) x sparse B ----
// A,B 5 nonzeros each: (m00,m02,m11,m20,m22). Row stride 3SP, col stride SP.
template<int SP>
__device__ __forceinline__ void sqf_nonet(float2* __restrict__ psi, int base,
                                          const float2* __restrict__ A) {
  float2 A00=A[0],A02=A[1],A11=A[2],A20=A[3],A22=A[4];
  float2 B00=A[5],B02=A[6],B11=A[7],B20=A[8],B22=A[9];
  float2 v[3][3];
#pragma unroll
  for (int j = 0; j < 3; ++j)
#pragma unroll
    for (int jb = 0; jb < 3; ++jb) v[j][jb] = psi[base + j*3*SP + jb*SP];
  float2 t[3][3];
#pragma unroll
  for (int j = 0; j < 3; ++j) {
    t[j][0] = cadd(cmul(B00,v[j][0]), cmul(B02,v[j][2]));
    t[j][1] = cmul(B11,v[j][1]);
    t[j][2] = cadd(cmul(B20,v[j][0]), cmul(B22,v[j][2]));
  }
#pragma unroll
  for (int ib = 0; ib < 3; ++ib) {
    psi[base + ib*SP]        = cadd(cmul(A00,t[0][ib]), cmul(A02,t[2][ib]));
    psi[base + 3*SP + ib*SP] = cmul(A11,t[1][ib]);
    psi[base + 6*SP + ib*SP] = cadd(cmul(A20,t[0][ib]), cmul(A22,t[2][ib]));
  }
}

// ---- fused disp(+phase+kerr) on one nonet: dense A (mode a) x dense B ----
template<int SP>
__device__ __forceinline__ void dpf_nonet(float2* __restrict__ psi, int base,
                                          const float2* __restrict__ A) {
  const float2* Bm = A + 9;
  float2 v[3][3];
#pragma unroll
  for (int j = 0; j < 3; ++j)
#pragma unroll
    for (int jb = 0; jb < 3; ++jb) v[j][jb] = psi[base + j*3*SP + jb*SP];
  float2 t[3][3];
#pragma unroll
  for (int j = 0; j < 3; ++j)
#pragma unroll
    for (int ib = 0; ib < 3; ++ib)
      t[j][ib] = cadd(cadd(cmul(Bm[ib*3+0],v[j][0]), cmul(Bm[ib*3+1],v[j][1])),
                      cmul(Bm[ib*3+2],v[j][2]));
#pragma unroll
  for (int i = 0; i < 3; ++i)
#pragma unroll
    for (int ib = 0; ib < 3; ++ib)
      psi[base + i*3*SP + ib*SP] =
        cadd(cadd(cmul(A[i*3+0],t[0][ib]), cmul(A[i*3+1],t[1][ib])),
             cmul(A[i*3+2],t[2][ib]));
}

#define BASE4(g, s0,s1,s2,s3) ({ int _d=(g); int _b=(_d%3)*(s0); _d/=3; \
  _b += (_d%3)*(s1); _d/=3; _b += (_d%3)*(s2); _d/=3; _b += (_d%3)*(s3); _b; })
#define BASE5(g, s0,s1,s2,s3,s4) ({ int _d=(g); int _b=(_d%3)*(s0); _d/=3; \
  _b += (_d%3)*(s1); _d/=3; _b += (_d%3)*(s2); _d/=3; _b += (_d%3)*(s3); _d/=3; \
  _b += (_d%3)*(s4); _b; })

// gtab layout (float2):
// [0,180)    BS (c,s):      idx = L*30 + pass*15 + n
// [180,360)  SQM (5/mode):  180 + (L*6+mode)*5  (m00,m02,m11,m20,m22)
// [360,684)  DPM (9/mode):  360 + (L*6+mode)*9  (i*3+j)
// [684,690)  init disp (sw,cw) per mode
__global__ __launch_bounds__(64)
void cvnn_kernel(const float* __restrict__ x,
                 const float* __restrict__ th1,
                 const float* __restrict__ th2,
                 const float* __restrict__ sr,
                 const float* __restrict__ dr,
                 const float* __restrict__ kp,
                 float* __restrict__ out) {
  __shared__ float2 psi[729];
  __shared__ float2 gtab[690];

  const int lane = threadIdx.x;
  const int bidx = blockIdx.x;

  // ---- build gate table ----
  for (int f = lane; f < 690; f += 64) {
    float sn, cn; float2 v;
    if (f < 180) {
      int L = f/30, r2 = f%30, pass = r2/15, n = r2%15;
      float th = (pass ? th2 : th1)[L*35 + n];
      sincosf(th, &sn, &cn); v = make_float2(cn, sn);
    } else if (f < 360) {
      int idx = f - 180; int Lm = idx/5, e = idx%5;
      int L = Lm/6, mode = Lm%6;
      float Sq, Cq; sincosf(0.25f*SQRT2f*sr[L*6+mode], &Sq, &Cq);
      float2 ph = make_float2(1.f, 0.f);
      if (mode < 5) { float ps, pc; sincosf(th1[L*35+29+mode], &ps, &pc);
                      ph = make_float2(pc, ps); }
      float2 ph2 = cmul(ph, ph);
      if      (e == 0) v = make_float2(Cq, 0.f);
      else if (e == 1) v = make_float2(Sq*ph2.x, Sq*ph2.y);
      else if (e == 2) v = ph;
      else if (e == 3) v = make_float2(-Sq, 0.f);
      else             v = make_float2(Cq*ph2.x, Cq*ph2.y);
    } else if (f < 684) {
      int idx = f - 360; int Lm = idx/9, e = idx%9;
      int L = Lm/6, mode = Lm%6; int i = e/3, j = e%3;
      sincosf(SQRT3f*dr[L*6+mode], &sn, &cn);
      float sw = sn*(1.f/SQRT3f), cw = (1.f-cn)*(1.f/3.f);
      float U;
      if      (i==0) U = (j==0) ? (1.f-cw)     : (j==1) ? (-sw)         : (SQRT2f*cw);
      else if (i==1) U = (j==0) ? (sw)         : (j==1) ? (1.f-3.f*cw)  : (-SQRT2f*sw);
      else           U = (j==0) ? (SQRT2f*cw)  : (j==1) ? (SQRT2f*sw)   : (1.f-2.f*cw);
      float2 ph = make_float2(1.f, 0.f);
      if (mode < 5) { float ps, pc; sincosf(th2[L*35+29+mode], &ps, &pc);
                      ph = make_float2(pc, ps); }
      float2 phj = (j==0) ? make_float2(1.f,0.f) : (j==1) ? ph : cmul(ph, ph);
      float ks, kc; sincosf(0.001f*kp[L*6+mode], &ks, &kc);
      float2 k1 = make_float2(kc, ks);
      float2 ki = (i==0) ? make_float2(1.f,0.f)
                : (i==1) ? k1 : cmul(cmul(k1,k1), cmul(k1,k1));
      float2 t = cmul(phj, ki);
      v = make_float2(U*t.x, U*t.y);
    } else {
      int mode = f - 684;
      sincosf(SQRT3f*x[bidx*6 + mode], &sn, &cn);
      v = make_float2(sn*(1.f/SQRT3f), (1.f-cn)*(1.f/3.f));
    }
    gtab[f] = v;
  }
  __syncthreads();

  // ---- init: product state of displaced |0> ----
  for (int idx = lane; idx < 729; idx += 64) {
    float pr = 1.f; int d = idx;
#pragma unroll
    for (int mm = 5; mm >= 0; --mm) {
      int n = d % 3; d /= 3;
      float2 dc = gtab[684 + mm];
      pr *= (n==0) ? (1.f-dc.y) : (n==1) ? dc.x : SQRT2f*dc.y;
    }
    psi[idx] = make_float2(pr, 0.f);
  }

  // ---- per-lane nonet bases (group id g = lane and lane+64) ----
  const bool two = (lane < 17);   // 81 = 64 + 17 groups per sweep
  const int l2 = lane + 64;
  // BS pair k: acted strides (3SP,SP); base = combo of remaining 4 mode strides
  const int b0_0 = lane;                          // k=0 SP=81 (rem 27,9,3,1)
  const int b0_1 = l2;
  const int b1_0 = BASE4(lane, 1, 3, 9, 243);     // k=1 SP=27 (rem 243,9,3,1)
  const int b1_1 = BASE4(l2,   1, 3, 9, 243);
  const int b2_0 = BASE4(lane, 1, 3, 81, 243);    // k=2 SP=9  (rem 243,81,3,1)
  const int b2_1 = BASE4(l2,   1, 3, 81, 243);
  const int b3_0 = BASE4(lane, 1, 27, 81, 243);   // k=3 SP=3  (rem 243,81,27,1)
  const int b3_1 = BASE4(l2,   1, 27, 81, 243);
  const int b4_0 = BASE4(lane, 9, 27, 81, 243);   // k=4 SP=1  (rem 243,81,27,9)
  const int b4_1 = BASE4(l2,   9, 27, 81, 243);
  __syncthreads();

#define BSSWEEP(SP, B0, B1, IDX) { float2 cs_ = gtab[IDX]; \
    bs_nonet<SP>(psi, B0, cs_); \
    if (two) bs_nonet<SP>(psi, B1, cs_); \
    __syncthreads(); }
#define SQSWEEP(SP, B0, B1, LL, m) { const float2* A_ = &gtab[180 + ((LL)*6+(m))*5]; \
    sqf_nonet<SP>(psi, B0, A_); \
    if (two) sqf_nonet<SP>(psi, B1, A_); \
    __syncthreads(); }
#define DPSWEEP(SP, B0, B1, LL, m) { const float2* A_ = &gtab[360 + ((LL)*6+(m))*9]; \
    dpf_nonet<SP>(psi, B0, A_); \
    if (two) dpf_nonet<SP>(psi, B1, A_); \
    __syncthreads(); }

  for (int L = 0; L < 6; ++L) {
    {  // pass 1: interferometer(theta_1), then squeeze (+phases folded)
      const int o = L*30;
      BSSWEEP(81, b0_0, b0_1, o+0);  BSSWEEP(9, b2_0, b2_1, o+1);
      BSSWEEP(1,  b4_0, b4_1, o+2);  BSSWEEP(27, b1_0, b1_1, o+3);
      BSSWEEP(3,  b3_0, b3_1, o+4);
      BSSWEEP(81, b0_0, b0_1, o+5);  BSSWEEP(9, b2_0, b2_1, o+6);
      BSSWEEP(1,  b4_0, b4_1, o+7);  BSSWEEP(27, b1_0, b1_1, o+8);
      BSSWEEP(3,  b3_0, b3_1, o+9);
      BSSWEEP(81, b0_0, b0_1, o+10); BSSWEEP(9, b2_0, b2_1, o+11);
      BSSWEEP(1,  b4_0, b4_1, o+12); BSSWEEP(27, b1_0, b1_1, o+13);
      BSSWEEP(3,  b3_0, b3_1, o+14);
      SQSWEEP(81, b0_0, b0_1, L, 0); SQSWEEP(9, b2_0, b2_1, L, 2);
      SQSWEEP(1,  b4_0, b4_1, L, 4);
    }
    {  // pass 2: interferometer(theta_2), then disp+kerr (+phases folded)
      const int o = L*30 + 15;
      BSSWEEP(81, b0_0, b0_1, o+0);  BSSWEEP(9, b2_0, b2_1, o+1);
      BSSWEEP(1,  b4_0, b4_1, o+2);  BSSWEEP(27, b1_0, b1_1, o+3);
      BSSWEEP(3,  b3_0, b3_1, o+4);
      BSSWEEP(81, b0_0, b0_1, o+5);  BSSWEEP(9, b2_0, b2_1, o+6);
      BSSWEEP(1,  b4_0, b4_1, o+7);  BSSWEEP(27, b1_0, b1_1, o+8);
      BSSWEEP(3,  b3_0, b3_1, o+9);
      BSSWEEP(81, b0_0, b0_1, o+10); BSSWEEP(9, b2_0, b2_1, o+11);
      BSSWEEP(1,  b4_0, b4_1, o+12); BSSWEEP(27, b1_0, b1_1, o+13);
      BSSWEEP(3,  b3_0, b3_1, o+14);
      DPSWEEP(81, b0_0, b0_1, L, 0); DPSWEEP(9, b2_0, b2_1, L, 2);
      DPSWEEP(1,  b4_0, b4_1, L, 4);
    }
  }

  // ---- <X_m> = sum 2Re(psi0* psi1) + 2*sqrt2*Re(psi1* psi2) per mode ----
  float xs[6] = {0.f, 0.f, 0.f, 0.f, 0.f, 0.f};
  for (int it = 0; it < 4; ++it) {
    int t = lane + (it << 6);
    if (t < 243) {
#define XACC(m, SS, BB) { int b_ = (BB); \
      float2 a_ = psi[b_]; float2 b2_ = psi[b_+(SS)]; float2 c_ = psi[b_+2*(SS)]; \
      xs[m] += 2.f*(a_.x*b2_.x + a_.y*b2_.y) + 2.f*SQRT2f*(b2_.x*c_.x + b2_.y*c_.y); }
      XACC(0, 243, BASE5(t, 1, 3, 9, 27, 81));
      XACC(1, 81,  BASE5(t, 1, 3, 9, 27, 243));
      XACC(2, 27,  BASE5(t, 1, 3, 9, 81, 243));
      XACC(3, 9,   BASE5(t, 1, 3, 27, 81, 243));
      XACC(4, 3,   BASE5(t, 1, 9, 27, 81, 243));
      XACC(5, 1,   BASE5(t, 3, 9, 27, 81, 243));
    }
  }
#pragma unroll
  for (int m = 0; m < 6; ++m) {
    float v = xs[m];
    for (int off = 32; off > 0; off >>= 1) v += __shfl_down(v, off);
    if (lane == 0) out[bidx*6 + m] = v;
  }
}

extern "C" void kernel_launch(void* const* d_in, const int* in_sizes, int n_in,
                              void* d_out, int out_size, void* d_ws, size_t ws_size,
                              hipStream_t stream) {
  const float* x  = (const float*)d_in[0];
  const float* t1 = (const float*)d_in[1];
  const float* t2 = (const float*)d_in[2];
  const float* sr = (const float*)d_in[3];
  const float* dr = (const float*)d_in[4];
  const float* kp = (const float*)d_in[5];
  const int B = in_sizes[0] / 6;
  cvnn_kernel<<<B, 64, 0, stream>>>(x, t1, t2, sr, dr, kp, (float*)d_out);
}

// Round 7
// 99.717 us; speedup vs baseline: 1.7477x; 1.2461x over previous
//
#include <hip/hip_runtime.h>

#define SQRT2f 1.41421356237309515f
#define SQRT3f 1.73205080756887729f

__device__ __forceinline__ float2 cmul(float2 a, float2 b) {
  return make_float2(a.x*b.x - a.y*b.y, a.x*b.y + a.y*b.x);
}
__device__ __forceinline__ float2 cadd(float2 a, float2 b) {
  return make_float2(a.x + b.x, a.y + b.y);
}

// ---- full 9x9 beamsplitter on one nonet, in place (rows 0,8 identity) ----
template<int SP>
__device__ __forceinline__ void bs_nonet(float2* __restrict__ psi, int base,
                                         float2 cs) {
  const float c = cs.x, s = cs.y;
  const float c2 = c*c - s*s, s2 = 2.f*c*s;
  const float cc = c*c, ss = s*s, rcs = SQRT2f*c*s;
  float2 a1 = psi[base+SP],   a3 = psi[base+3*SP];
  float2 a2 = psi[base+2*SP], a4 = psi[base+4*SP], a6 = psi[base+6*SP];
  float2 a5 = psi[base+5*SP], a7 = psi[base+7*SP];
  psi[base+SP]   = make_float2(c*a1.x - s*a3.x, c*a1.y - s*a3.y);
  psi[base+3*SP] = make_float2(s*a1.x + c*a3.x, s*a1.y + c*a3.y);
  psi[base+2*SP] = make_float2(cc*a2.x - rcs*a4.x + ss*a6.x,
                               cc*a2.y - rcs*a4.y + ss*a6.y);
  psi[base+4*SP] = make_float2(rcs*a2.x + c2*a4.x - rcs*a6.x,
                               rcs*a2.y + c2*a4.y - rcs*a6.y);
  psi[base+6*SP] = make_float2(ss*a2.x + rcs*a4.x + cc*a6.x,
                               ss*a2.y + rcs*a4.y + cc*a6.y);
  psi[base+5*SP] = make_float2(c2*a5.x - s2*a7.x, c2*a5.y - s2*a7.y);
  psi[base+7*SP] = make_float2(s2*a5.x + c2*a7.x, s2*a5.y + c2*a7.y);
}

// ---- fused squeeze(+phase) on one nonet: sparse A (mode a) x sparse B ----
template<int SP>
__device__ __forceinline__ void sqf_nonet(float2* __restrict__ psi, int base,
                                          const float2* __restrict__ A) {
  float2 A00=A[0],A02=A[1],A11=A[2],A20=A[3],A22=A[4];
  float2 B00=A[5],B02=A[6],B11=A[7],B20=A[8],B22=A[9];
  float2 v[3][3];
#pragma unroll
  for (int j = 0; j < 3; ++j)
#pragma unroll
    for (int jb = 0; jb < 3; ++jb) v[j][jb] = psi[base + j*3*SP + jb*SP];
  float2 t[3][3];
#pragma unroll
  for (int j = 0; j < 3; ++j) {
    t[j][0] = cadd(cmul(B00,v[j][0]), cmul(B02,v[j][2]));
    t[j][1] = cmul(B11,v[j][1]);
    t[j][2] = cadd(cmul(B20,v[j][0]), cmul(B22,v[j][2]));
  }
#pragma unroll
  for (int ib = 0; ib < 3; ++ib) {
    psi[base + ib*SP]        = cadd(cmul(A00,t[0][ib]), cmul(A02,t[2][ib]));
    psi[base + 3*SP + ib*SP] = cmul(A11,t[1][ib]);
    psi[base + 6*SP + ib*SP] = cadd(cmul(A20,t[0][ib]), cmul(A22,t[2][ib]));
  }
}

// ---- fused disp(+phase+kerr) on one nonet: dense A (mode a) x dense B ----
template<int SP>
__device__ __forceinline__ void dpf_nonet(float2* __restrict__ psi, int base,
                                          const float2* __restrict__ A) {
  const float2* Bm = A + 9;
  float2 v[3][3];
#pragma unroll
  for (int j = 0; j < 3; ++j)
#pragma unroll
    for (int jb = 0; jb < 3; ++jb) v[j][jb] = psi[base + j*3*SP + jb*SP];
  float2 t[3][3];
#pragma unroll
  for (int j = 0; j < 3; ++j)
#pragma unroll
    for (int ib = 0; ib < 3; ++ib)
      t[j][ib] = cadd(cadd(cmul(Bm[ib*3+0],v[j][0]), cmul(Bm[ib*3+1],v[j][1])),
                      cmul(Bm[ib*3+2],v[j][2]));
#pragma unroll
  for (int i = 0; i < 3; ++i)
#pragma unroll
    for (int ib = 0; ib < 3; ++ib)
      psi[base + i*3*SP + ib*SP] =
        cadd(cadd(cmul(A[i*3+0],t[0][ib]), cmul(A[i*3+1],t[1][ib])),
             cmul(A[i*3+2],t[2][ib]));
}

#define BASE4(g, s0,s1,s2,s3) ({ int _d=(g); int _b=(_d%3)*(s0); _d/=3; \
  _b += (_d%3)*(s1); _d/=3; _b += (_d%3)*(s2); _d/=3; _b += (_d%3)*(s3); _b; })
#define BASE5(g, s0,s1,s2,s3,s4) ({ int _d=(g); int _b=(_d%3)*(s0); _d/=3; \
  _b += (_d%3)*(s1); _d/=3; _b += (_d%3)*(s2); _d/=3; _b += (_d%3)*(s3); _d/=3; \
  _b += (_d%3)*(s4); _b; })

// gtab layout (float2):
// [0,180)    BS (c,s):      idx = L*30 + pass*15 + n
// [180,360)  SQM (5/mode):  180 + (L*6+mode)*5  (m00,m02,m11,m20,m22)
// [360,684)  DPM (9/mode):  360 + (L*6+mode)*9  (i*3+j)
// [684,690)  init disp (sw,cw) per mode
__global__ __launch_bounds__(128)
void cvnn_kernel(const float* __restrict__ x,
                 const float* __restrict__ th1,
                 const float* __restrict__ th2,
                 const float* __restrict__ sr,
                 const float* __restrict__ dr,
                 const float* __restrict__ kp,
                 float* __restrict__ out) {
  __shared__ float2 psi[729];
  __shared__ float2 gtab[690];
  __shared__ float red[12];

  const int tid = threadIdx.x;
  const int bidx = blockIdx.x;

  // ---- build gate table ----
  for (int f = tid; f < 690; f += 128) {
    float sn, cn; float2 v;
    if (f < 180) {
      int L = f/30, r2 = f%30, pass = r2/15, n = r2%15;
      float th = (pass ? th2 : th1)[L*35 + n];
      sincosf(th, &sn, &cn); v = make_float2(cn, sn);
    } else if (f < 360) {
      int idx = f - 180; int Lm = idx/5, e = idx%5;
      int L = Lm/6, mode = Lm%6;
      float Sq, Cq; sincosf(0.25f*SQRT2f*sr[L*6+mode], &Sq, &Cq);
      float2 ph = make_float2(1.f, 0.f);
      if (mode < 5) { float ps, pc; sincosf(th1[L*35+29+mode], &ps, &pc);
                      ph = make_float2(pc, ps); }
      float2 ph2 = cmul(ph, ph);
      if      (e == 0) v = make_float2(Cq, 0.f);
      else if (e == 1) v = make_float2(Sq*ph2.x, Sq*ph2.y);
      else if (e == 2) v = ph;
      else if (e == 3) v = make_float2(-Sq, 0.f);
      else             v = make_float2(Cq*ph2.x, Cq*ph2.y);
    } else if (f < 684) {
      int idx = f - 360; int Lm = idx/9, e = idx%9;
      int L = Lm/6, mode = Lm%6; int i = e/3, j = e%3;
      sincosf(SQRT3f*dr[L*6+mode], &sn, &cn);
      float sw = sn*(1.f/SQRT3f), cw = (1.f-cn)*(1.f/3.f);
      float U;
      if      (i==0) U = (j==0) ? (1.f-cw)     : (j==1) ? (-sw)         : (SQRT2f*cw);
      else if (i==1) U = (j==0) ? (sw)         : (j==1) ? (1.f-3.f*cw)  : (-SQRT2f*sw);
      else           U = (j==0) ? (SQRT2f*cw)  : (j==1) ? (SQRT2f*sw)   : (1.f-2.f*cw);
      float2 ph = make_float2(1.f, 0.f);
      if (mode < 5) { float ps, pc; sincosf(th2[L*35+29+mode], &ps, &pc);
                      ph = make_float2(pc, ps); }
      float2 phj = (j==0) ? make_float2(1.f,0.f) : (j==1) ? ph : cmul(ph, ph);
      float ks, kc; sincosf(0.001f*kp[L*6+mode], &ks, &kc);
      float2 k1 = make_float2(kc, ks);
      float2 ki = (i==0) ? make_float2(1.f,0.f)
                : (i==1) ? k1 : cmul(cmul(k1,k1), cmul(k1,k1));
      float2 t = cmul(phj, ki);
      v = make_float2(U*t.x, U*t.y);
    } else {
      int mode = f - 684;
      sincosf(SQRT3f*x[bidx*6 + mode], &sn, &cn);
      v = make_float2(sn*(1.f/SQRT3f), (1.f-cn)*(1.f/3.f));
    }
    gtab[f] = v;
  }
  __syncthreads();

  // ---- init: product state of displaced |0> ----
  for (int idx = tid; idx < 729; idx += 128) {
    float pr = 1.f; int d = idx;
#pragma unroll
    for (int mm = 5; mm >= 0; --mm) {
      int n = d % 3; d /= 3;
      float2 dc = gtab[684 + mm];
      pr *= (n==0) ? (1.f-dc.y) : (n==1) ? dc.x : SQRT2f*dc.y;
    }
    psi[idx] = make_float2(pr, 0.f);
  }

  // ---- per-thread nonet bases: one nonet per active thread (tid < 81) ----
  const bool act = (tid < 81);
  const int g = (tid < 81) ? tid : 0;
  const int b0 = g;                          // k=0 SP=81 (rem 27,9,3,1)
  const int b1 = BASE4(g, 1, 3, 9, 243);     // k=1 SP=27 (rem 243,9,3,1)
  const int b2 = BASE4(g, 1, 3, 81, 243);    // k=2 SP=9  (rem 243,81,3,1)
  const int b3 = BASE4(g, 1, 27, 81, 243);   // k=3 SP=3  (rem 243,81,27,1)
  const int b4 = BASE4(g, 9, 27, 81, 243);   // k=4 SP=1  (rem 243,81,27,9)
  __syncthreads();

#define BSSWEEP(SP, BB, IDX) { if (act) { float2 cs_ = gtab[IDX]; \
    bs_nonet<SP>(psi, BB, cs_); } __syncthreads(); }
#define SQSWEEP(SP, BB, LL, m) { if (act) { \
    const float2* A_ = &gtab[180 + ((LL)*6+(m))*5]; \
    sqf_nonet<SP>(psi, BB, A_); } __syncthreads(); }
#define DPSWEEP(SP, BB, LL, m) { if (act) { \
    const float2* A_ = &gtab[360 + ((LL)*6+(m))*9]; \
    dpf_nonet<SP>(psi, BB, A_); } __syncthreads(); }

  for (int L = 0; L < 6; ++L) {
    {  // pass 1: interferometer(theta_1), then squeeze (+phases folded)
      const int o = L*30;
      BSSWEEP(81, b0, o+0);  BSSWEEP(9, b2, o+1);  BSSWEEP(1, b4, o+2);
      BSSWEEP(27, b1, o+3);  BSSWEEP(3, b3, o+4);
      BSSWEEP(81, b0, o+5);  BSSWEEP(9, b2, o+6);  BSSWEEP(1, b4, o+7);
      BSSWEEP(27, b1, o+8);  BSSWEEP(3, b3, o+9);
      BSSWEEP(81, b0, o+10); BSSWEEP(9, b2, o+11); BSSWEEP(1, b4, o+12);
      BSSWEEP(27, b1, o+13); BSSWEEP(3, b3, o+14);
      SQSWEEP(81, b0, L, 0); SQSWEEP(9, b2, L, 2); SQSWEEP(1, b4, L, 4);
    }
    {  // pass 2: interferometer(theta_2), then disp+kerr (+phases folded)
      const int o = L*30 + 15;
      BSSWEEP(81, b0, o+0);  BSSWEEP(9, b2, o+1);  BSSWEEP(1, b4, o+2);
      BSSWEEP(27, b1, o+3);  BSSWEEP(3, b3, o+4);
      BSSWEEP(81, b0, o+5);  BSSWEEP(9, b2, o+6);  BSSWEEP(1, b4, o+7);
      BSSWEEP(27, b1, o+8);  BSSWEEP(3, b3, o+9);
      BSSWEEP(81, b0, o+10); BSSWEEP(9, b2, o+11); BSSWEEP(1, b4, o+12);
      BSSWEEP(27, b1, o+13); BSSWEEP(3, b3, o+14);
      DPSWEEP(81, b0, L, 0); DPSWEEP(9, b2, L, 2); DPSWEEP(1, b4, L, 4);
    }
  }

  // ---- <X_m> = sum 2Re(psi0* psi1) + 2*sqrt2*Re(psi1* psi2) per mode ----
  float xs[6] = {0.f, 0.f, 0.f, 0.f, 0.f, 0.f};
  for (int it = 0; it < 2; ++it) {
    int t = tid + (it << 7);
    if (t < 243) {
#define XACC(m, SS, BB) { int b_ = (BB); \
      float2 a_ = psi[b_]; float2 b2_ = psi[b_+(SS)]; float2 c_ = psi[b_+2*(SS)]; \
      xs[m] += 2.f*(a_.x*b2_.x + a_.y*b2_.y) + 2.f*SQRT2f*(b2_.x*c_.x + b2_.y*c_.y); }
      XACC(0, 243, BASE5(t, 1, 3, 9, 27, 81));
      XACC(1, 81,  BASE5(t, 1, 3, 9, 27, 243));
      XACC(2, 27,  BASE5(t, 1, 3, 9, 81, 243));
      XACC(3, 9,   BASE5(t, 1, 3, 27, 81, 243));
      XACC(4, 3,   BASE5(t, 1, 9, 27, 81, 243));
      XACC(5, 1,   BASE5(t, 3, 9, 27, 81, 243));
    }
  }
  const int lane = tid & 63, wid = tid >> 6;
#pragma unroll
  for (int m = 0; m < 6; ++m) {
    float v = xs[m];
    for (int off = 32; off > 0; off >>= 1) v += __shfl_down(v, off);
    if (lane == 0) red[wid*6 + m] = v;
  }
  __syncthreads();
  if (tid < 6) out[bidx*6 + tid] = red[tid] + red[6 + tid];
}

extern "C" void kernel_launch(void* const* d_in, const int* in_sizes, int n_in,
                              void* d_out, int out_size, void* d_ws, size_t ws_size,
                              hipStream_t stream) {
  const float* x  = (const float*)d_in[0];
  const float* t1 = (const float*)d_in[1];
  const float* t2 = (const float*)d_in[2];
  const float* sr = (const float*)d_in[3];
  const float* dr = (const float*)d_in[4];
  const float* kp = (const float*)d_in[5];
  const int B = in_sizes[0] / 6;
  cvnn_kernel<<<B, 128, 0, stream>>>(x, t1, t2, sr, dr, kp, (float*)d_out);
}

// Round 8
// 92.855 us; speedup vs baseline: 1.8768x; 1.0739x over previous
//
#include <hip/hip_runtime.h>

#define SQRT2f 1.41421356237309515f
#define SQRT3f 1.73205080756887729f

__device__ __forceinline__ float2 cmul(float2 a, float2 b) {
  return make_float2(a.x*b.x - a.y*b.y, a.x*b.y + a.y*b.x);
}
__device__ __forceinline__ float2 cadd(float2 a, float2 b) {
  return make_float2(a.x + b.x, a.y + b.y);
}

// ---- BS 9x9 on a register 9-vector q[3*na+nb] (rows 0,8 identity) ----
__device__ __forceinline__ void bs_q(float2 q[9], float2 cs) {
  const float c = cs.x, s = cs.y;
  const float c2 = c*c - s*s, s2 = 2.f*c*s;
  const float cc = c*c, ss = s*s, rcs = SQRT2f*c*s;
  float2 a1=q[1], a3=q[3], a2=q[2], a4=q[4], a6=q[6], a5=q[5], a7=q[7];
  q[1] = make_float2(c*a1.x - s*a3.x, c*a1.y - s*a3.y);
  q[3] = make_float2(s*a1.x + c*a3.x, s*a1.y + c*a3.y);
  q[2] = make_float2(cc*a2.x - rcs*a4.x + ss*a6.x, cc*a2.y - rcs*a4.y + ss*a6.y);
  q[4] = make_float2(rcs*a2.x + c2*a4.x - rcs*a6.x, rcs*a2.y + c2*a4.y - rcs*a6.y);
  q[6] = make_float2(ss*a2.x + rcs*a4.x + cc*a6.x, ss*a2.y + rcs*a4.y + cc*a6.y);
  q[5] = make_float2(c2*a5.x - s2*a7.x, c2*a5.y - s2*a7.y);
  q[7] = make_float2(s2*a5.x + c2*a7.x, s2*a5.y + c2*a7.y);
}

// ---- plain BS nonet, in place ----
template<int SP>
__device__ __forceinline__ void bs_nonet(float2* __restrict__ psi, int base,
                                         float2 cs) {
  const float c = cs.x, s = cs.y;
  const float c2 = c*c - s*s, s2 = 2.f*c*s;
  const float cc = c*c, ss = s*s, rcs = SQRT2f*c*s;
  float2 a1 = psi[base+SP],   a3 = psi[base+3*SP];
  float2 a2 = psi[base+2*SP], a4 = psi[base+4*SP], a6 = psi[base+6*SP];
  float2 a5 = psi[base+5*SP], a7 = psi[base+7*SP];
  psi[base+SP]   = make_float2(c*a1.x - s*a3.x, c*a1.y - s*a3.y);
  psi[base+3*SP] = make_float2(s*a1.x + c*a3.x, s*a1.y + c*a3.y);
  psi[base+2*SP] = make_float2(cc*a2.x - rcs*a4.x + ss*a6.x,
                               cc*a2.y - rcs*a4.y + ss*a6.y);
  psi[base+4*SP] = make_float2(rcs*a2.x + c2*a4.x - rcs*a6.x,
                               rcs*a2.y + c2*a4.y - rcs*a6.y);
  psi[base+6*SP] = make_float2(ss*a2.x + rcs*a4.x + cc*a6.x,
                               ss*a2.y + rcs*a4.y + cc*a6.y);
  psi[base+5*SP] = make_float2(c2*a5.x - s2*a7.x, c2*a5.y - s2*a7.y);
  psi[base+7*SP] = make_float2(s2*a5.x + c2*a7.x, s2*a5.y + c2*a7.y);
}

// ---- fused (A dense ⊗ B dense) then BS, in place. G = A(9),B(9) ----
template<int SP>
__device__ __forceinline__ void dpbs_nonet(float2* __restrict__ psi, int base,
                                           const float2* __restrict__ G,
                                           float2 cs) {
  const float2* A = G; const float2* B = G + 9;
  float2 v[3][3];
#pragma unroll
  for (int j = 0; j < 3; ++j)
#pragma unroll
    for (int jb = 0; jb < 3; ++jb) v[j][jb] = psi[base + j*3*SP + jb*SP];
  float2 t[3][3];
#pragma unroll
  for (int j = 0; j < 3; ++j)
#pragma unroll
    for (int ib = 0; ib < 3; ++ib)
      t[j][ib] = cadd(cadd(cmul(B[ib*3+0],v[j][0]), cmul(B[ib*3+1],v[j][1])),
                      cmul(B[ib*3+2],v[j][2]));
  float2 q[9];
#pragma unroll
  for (int i = 0; i < 3; ++i)
#pragma unroll
    for (int ib = 0; ib < 3; ++ib)
      q[i*3+ib] = cadd(cadd(cmul(A[i*3+0],t[0][ib]), cmul(A[i*3+1],t[1][ib])),
                       cmul(A[i*3+2],t[2][ib]));
  bs_q(q, cs);
#pragma unroll
  for (int i = 0; i < 3; ++i)
#pragma unroll
    for (int ib = 0; ib < 3; ++ib) psi[base + i*3*SP + ib*SP] = q[i*3+ib];
}

// ---- fused (A sparse ⊗ B sparse SQ) then BS. G = A(5),B(5): m00,m02,m11,m20,m22 ----
template<int SP>
__device__ __forceinline__ void sqbs_nonet(float2* __restrict__ psi, int base,
                                           const float2* __restrict__ G,
                                           float2 cs) {
  float2 A00=G[0],A02=G[1],A11=G[2],A20=G[3],A22=G[4];
  float2 B00=G[5],B02=G[6],B11=G[7],B20=G[8],B22=G[9];
  float2 v[3][3];
#pragma unroll
  for (int j = 0; j < 3; ++j)
#pragma unroll
    for (int jb = 0; jb < 3; ++jb) v[j][jb] = psi[base + j*3*SP + jb*SP];
  float2 t[3][3];
#pragma unroll
  for (int j = 0; j < 3; ++j) {
    t[j][0] = cadd(cmul(B00,v[j][0]), cmul(B02,v[j][2]));
    t[j][1] = cmul(B11,v[j][1]);
    t[j][2] = cadd(cmul(B20,v[j][0]), cmul(B22,v[j][2]));
  }
  float2 q[9];
#pragma unroll
  for (int ib = 0; ib < 3; ++ib) {
    q[ib]   = cadd(cmul(A00,t[0][ib]), cmul(A02,t[2][ib]));
    q[3+ib] = cmul(A11,t[1][ib]);
    q[6+ib] = cadd(cmul(A20,t[0][ib]), cmul(A22,t[2][ib]));
  }
  bs_q(q, cs);
#pragma unroll
  for (int i = 0; i < 3; ++i)
#pragma unroll
    for (int ib = 0; ib < 3; ++ib) psi[base + i*3*SP + ib*SP] = q[i*3+ib];
}

#define BASE4(g, s0,s1,s2,s3) ({ int _d=(g); int _b=(_d%3)*(s0); _d/=3; \
  _b += (_d%3)*(s1); _d/=3; _b += (_d%3)*(s2); _d/=3; _b += (_d%3)*(s3); _b; })
#define BASE5(g, s0,s1,s2,s3,s4) ({ int _d=(g); int _b=(_d%3)*(s0); _d/=3; \
  _b += (_d%3)*(s1); _d/=3; _b += (_d%3)*(s2); _d/=3; _b += (_d%3)*(s3); _d/=3; \
  _b += (_d%3)*(s4); _b; })

// DPK(L,mode)[i][j] = Kerr_i * U_disp[i][j] * phase^j (th2-layer phases)
__device__ __forceinline__ float2 dpk_entry(const float* __restrict__ dr,
                                            const float* __restrict__ th2,
                                            const float* __restrict__ kp,
                                            int L, int mode, int i, int j) {
  float sn, cn; sincosf(SQRT3f*dr[L*6+mode], &sn, &cn);
  float sw = sn*(1.f/SQRT3f), cw = (1.f-cn)*(1.f/3.f);
  float U;
  if      (i==0) U = (j==0) ? (1.f-cw)     : (j==1) ? (-sw)         : (SQRT2f*cw);
  else if (i==1) U = (j==0) ? (sw)         : (j==1) ? (1.f-3.f*cw)  : (-SQRT2f*sw);
  else           U = (j==0) ? (SQRT2f*cw)  : (j==1) ? (SQRT2f*sw)   : (1.f-2.f*cw);
  float2 ph = make_float2(1.f, 0.f);
  if (mode < 5) { float ps, pc; sincosf(th2[L*35+29+mode], &ps, &pc);
                  ph = make_float2(pc, ps); }
  float2 phj = (j==0) ? make_float2(1.f,0.f) : (j==1) ? ph : cmul(ph, ph);
  float ks, kc; sincosf(0.001f*kp[L*6+mode], &ks, &kc);
  float2 k1 = make_float2(kc, ks);
  float2 ki = (i==0) ? make_float2(1.f,0.f)
            : (i==1) ? k1 : cmul(cmul(k1,k1), cmul(k1,k1));
  float2 t = cmul(phj, ki);
  return make_float2(U*t.x, U*t.y);
}

// gtab (float2):
// [0,180)   BS (c,s): idx = (L*2+pass)*15 + pos (pos = application order)
// [180,360) SQG: 180 + (L*3+c)*10 : A(5) mode 2c, B(5) mode 2c+1 (th1 phases folded)
// [360,630) DPG: 360 + (Ls*3+c)*18 : A(9) mode 2c, B(9) mode 2c+1 (layers 0..4)
// [630,684) Meas M_m = DPK(5,m)† X3 DPK(5,m): 630 + m*9 + i*3+j
// [684,690) init disp (sw,cw) per mode
__global__ __launch_bounds__(128)
void cvnn_kernel(const float* __restrict__ x,
                 const float* __restrict__ th1,
                 const float* __restrict__ th2,
                 const float* __restrict__ sr,
                 const float* __restrict__ dr,
                 const float* __restrict__ kp,
                 float* __restrict__ out) {
  __shared__ float2 psi[729];
  __shared__ float2 gtab[690];
  __shared__ float red[12];

  const int tid = threadIdx.x;
  const int bidx = blockIdx.x;

  // ---- build gate table ----
  for (int f = tid; f < 690; f += 128) {
    float sn, cn; float2 v;
    if (f < 180) {
      int Lp = f/15, pos = f%15;
      int L = Lp/2, pass = Lp%2;
      float th = (pass ? th2 : th1)[L*35 + pos];
      sincosf(th, &sn, &cn); v = make_float2(cn, sn);
    } else if (f < 360) {
      int i = f - 180; int Lc = i/10, e = i%10;
      int L = Lc/3, c3 = Lc%3;
      int mode = 2*c3 + (e >= 5); int ee = e%5;
      float Sq, Cq; sincosf(0.25f*SQRT2f*sr[L*6+mode], &Sq, &Cq);
      float2 ph = make_float2(1.f, 0.f);
      if (mode < 5) { float ps, pc; sincosf(th1[L*35+29+mode], &ps, &pc);
                      ph = make_float2(pc, ps); }
      float2 ph2 = cmul(ph, ph);
      if      (ee == 0) v = make_float2(Cq, 0.f);
      else if (ee == 1) v = make_float2(Sq*ph2.x, Sq*ph2.y);
      else if (ee == 2) v = ph;
      else if (ee == 3) v = make_float2(-Sq, 0.f);
      else              v = make_float2(Cq*ph2.x, Cq*ph2.y);
    } else if (f < 630) {
      int i = f - 360; int Ld = i/18, e = i%18;
      int Ls = Ld/3, c3 = Ld%3;
      int mode = 2*c3 + (e >= 9); int ee = e%9;
      v = dpk_entry(dr, th2, kp, Ls, mode, ee/3, ee%3);
    } else if (f < 684) {
      int i = f - 630; int m = i/9, e = i%9;
      int ii = e/3, jj = e%3;
      // M_ij = conj(D0i)D1j + conj(D1i)(D0j + √2 D2j) + √2 conj(D2i)D1j
      float2 D0i = dpk_entry(dr, th2, kp, 5, m, 0, ii);
      float2 D1i = dpk_entry(dr, th2, kp, 5, m, 1, ii);
      float2 D2i = dpk_entry(dr, th2, kp, 5, m, 2, ii);
      float2 D0j = dpk_entry(dr, th2, kp, 5, m, 0, jj);
      float2 D1j = dpk_entry(dr, th2, kp, 5, m, 1, jj);
      float2 D2j = dpk_entry(dr, th2, kp, 5, m, 2, jj);
      float2 c0 = make_float2(D0i.x, -D0i.y);
      float2 c1 = make_float2(D1i.x, -D1i.y);
      float2 c2 = make_float2(D2i.x, -D2i.y);
      float2 acc = cmul(c0, D1j);
      float2 tmp = make_float2(D0j.x + SQRT2f*D2j.x, D0j.y + SQRT2f*D2j.y);
      acc = cadd(acc, cmul(c1, tmp));
      acc = cadd(acc, cmul(c2, make_float2(SQRT2f*D1j.x, SQRT2f*D1j.y)));
      v = acc;
    } else {
      int mode = f - 684;
      sincosf(SQRT3f*x[bidx*6 + mode], &sn, &cn);
      v = make_float2(sn*(1.f/SQRT3f), (1.f-cn)*(1.f/3.f));
    }
    gtab[f] = v;
  }
  __syncthreads();

  // ---- init: product state of displaced |0> ----
  for (int idx = tid; idx < 729; idx += 128) {
    float pr = 1.f; int d = idx;
#pragma unroll
    for (int mm = 5; mm >= 0; --mm) {
      int n = d % 3; d /= 3;
      float2 dc = gtab[684 + mm];
      pr *= (n==0) ? (1.f-dc.y) : (n==1) ? dc.x : SQRT2f*dc.y;
    }
    psi[idx] = make_float2(pr, 0.f);
  }

  // ---- per-thread nonet bases: one nonet per active thread (tid < 81) ----
  const bool act = (tid < 81);
  const int g = (tid < 81) ? tid : 0;
  const int b0 = g;                          // k=0 SP=81
  const int b1 = BASE4(g, 1, 3, 9, 243);     // k=1 SP=27
  const int b2 = BASE4(g, 1, 3, 81, 243);    // k=2 SP=9
  const int b3 = BASE4(g, 1, 27, 81, 243);   // k=3 SP=3
  const int b4 = BASE4(g, 9, 27, 81, 243);   // k=4 SP=1
  __syncthreads();

  float2 csN = gtab[0];   // prefetch first sweep's (c,s)
  __syncthreads();

#define BSP(SP, BB, NEXT)  { if (act) bs_nonet<SP>(psi, BB, csN); \
    csN = gtab[NEXT]; __syncthreads(); }
#define DPBS(SP, BB, GI, NEXT) { if (act) dpbs_nonet<SP>(psi, BB, &gtab[GI], csN); \
    csN = gtab[NEXT]; __syncthreads(); }
#define SQBS(SP, BB, GI, NEXT) { if (act) sqbs_nonet<SP>(psi, BB, &gtab[GI], csN); \
    csN = gtab[NEXT]; __syncthreads(); }

#pragma unroll
  for (int L = 0; L < 6; ++L) {
    const int i1 = (L*2)*15, i2 = (L*2+1)*15;
    // pass 1: first course folds previous layer's DPK (L>=1)
    if (L == 0) {
      BSP(81, b0, i1+1); BSP(9, b2, i1+2); BSP(1, b4, i1+3);
    } else {
      const int gd = 360 + (L-1)*3*18;
      DPBS(81, b0, gd+0,  i1+1); DPBS(9, b2, gd+18, i1+2); DPBS(1, b4, gd+36, i1+3);
    }
    BSP(27, b1, i1+4);  BSP(3, b3, i1+5);
    BSP(81, b0, i1+6);  BSP(9, b2, i1+7);  BSP(1, b4, i1+8);
    BSP(27, b1, i1+9);  BSP(3, b3, i1+10);
    BSP(81, b0, i1+11); BSP(9, b2, i1+12); BSP(1, b4, i1+13);
    BSP(27, b1, i1+14); BSP(3, b3, i2+0);
    // pass 2: first course folds this layer's SQ (+th1 phases)
    {
      const int gs = 180 + L*3*10;
      SQBS(81, b0, gs+0, i2+1); SQBS(9, b2, gs+10, i2+2); SQBS(1, b4, gs+20, i2+3);
    }
    BSP(27, b1, i2+4);  BSP(3, b3, i2+5);
    BSP(81, b0, i2+6);  BSP(9, b2, i2+7);  BSP(1, b4, i2+8);
    BSP(27, b1, i2+9);  BSP(3, b3, i2+10);
    BSP(81, b0, i2+11); BSP(9, b2, i2+12); BSP(1, b4, i2+13);
    BSP(27, b1, i2+14); BSP(3, b3, (L < 5) ? (L+1)*30 : 0);
  }

  // ---- <X_m> via folded Hermitian M_m = DPK† X DPK ----
  float xs[6] = {0.f, 0.f, 0.f, 0.f, 0.f, 0.f};
  for (int it = 0; it < 2; ++it) {
    int t = tid + (it << 7);
    if (t < 243) {
#define XACC(m, SS, BB) { int b_ = (BB); \
      float2 a_ = psi[b_]; float2 e_ = psi[b_+(SS)]; float2 f_ = psi[b_+2*(SS)]; \
      const float2* M_ = &gtab[630 + (m)*9]; \
      float d0 = M_[0].x, d1 = M_[4].x, d2 = M_[8].x; \
      float2 M01 = M_[1], M02 = M_[2], M12 = M_[5]; \
      xs[m] += d0*(a_.x*a_.x + a_.y*a_.y) + d1*(e_.x*e_.x + e_.y*e_.y) \
             + d2*(f_.x*f_.x + f_.y*f_.y) \
        + 2.f*(M01.x*(a_.x*e_.x + a_.y*e_.y) - M01.y*(a_.x*e_.y - a_.y*e_.x)) \
        + 2.f*(M02.x*(a_.x*f_.x + a_.y*f_.y) - M02.y*(a_.x*f_.y - a_.y*f_.x)) \
        + 2.f*(M12.x*(e_.x*f_.x + e_.y*f_.y) - M12.y*(e_.x*f_.y - e_.y*f_.x)); }
      XACC(0, 243, BASE5(t, 1, 3, 9, 27, 81));
      XACC(1, 81,  BASE5(t, 1, 3, 9, 27, 243));
      XACC(2, 27,  BASE5(t, 1, 3, 9, 81, 243));
      XACC(3, 9,   BASE5(t, 1, 3, 27, 81, 243));
      XACC(4, 3,   BASE5(t, 1, 9, 27, 81, 243));
      XACC(5, 1,   BASE5(t, 3, 9, 27, 81, 243));
    }
  }
  const int lane = tid & 63, wid = tid >> 6;
#pragma unroll
  for (int m = 0; m < 6; ++m) {
    float v = xs[m];
    for (int off = 32; off > 0; off >>= 1) v += __shfl_down(v, off);
    if (lane == 0) red[wid*6 + m] = v;
  }
  __syncthreads();
  if (tid < 6) out[bidx*6 + tid] = red[tid] + red[6 + tid];
}

extern "C" void kernel_launch(void* const* d_in, const int* in_sizes, int n_in,
                              void* d_out, int out_size, void* d_ws, size_t ws_size,
                              hipStream_t stream) {
  const float* x  = (const float*)d_in[0];
  const float* t1 = (const float*)d_in[1];
  const float* t2 = (const float*)d_in[2];
  const float* sr = (const float*)d_in[3];
  const float* dr = (const float*)d_in[4];
  const float* kp = (const float*)d_in[5];
  const int B = in_sizes[0] / 6;
  cvnn_kernel<<<B, 128, 0, stream>>>(x, t1, t2, sr, dr, kp, (float*)d_out);
}